// Round 10
// baseline (570.892 us; speedup 1.0000x reference)
//
#include <hip/hip_runtime.h>
#include <math.h>

// SGD filter design: 999 sequential SGD steps on one SOS section (all 16
// provably identical), persistent single block, 256 threads (4 waves),
// 2 freqs/lane, DPP reductions, 1 barrier/iter.
// Round 10: m=r^8 via 3 squarings (-2 trans/freq), LR folded into loss
// constant (-5 muls on serial tail), coalesced LDS partials, unroll x2.

#define EPSF  1e-8f
// LR * K * C  = 2e-5 * 6.020599913279624 * 0.033929256398692726
#define LRKC_ 4.0854895573e-6f
// 1/K = 1/6.020599913279624
#define INVK_ 0.16609640474436813f

__device__ __forceinline__ float rcp_(float x)  { return __builtin_amdgcn_rcpf(x); }
__device__ __forceinline__ float sqrt_(float x) { return __builtin_amdgcn_sqrtf(x); }
__device__ __forceinline__ float log2_(float x) { return __builtin_amdgcn_logf(x); }
__device__ __forceinline__ float exp2_(float x) { return __builtin_amdgcn_exp2f(x); }

// tanh(u), u >= 0:  1 - 2/(exp(2u)+1)
__device__ __forceinline__ float tanh_pos(float u) {
    float e = exp2_(u * 2.8853900817779268f); // 2/ln2
    return 1.0f - 2.0f * rcp_(e + 1.0f);
}

template <int CTRL>
__device__ __forceinline__ float dpp_add(float x) {
    int y = __builtin_amdgcn_update_dpp(0, __float_as_int(x), CTRL, 0xF, 0xF, true);
    return x + __int_as_float(y);
}

// Full 64-lane sum; result valid at lane 63.
__device__ __forceinline__ float wave_sum_at63(float x) {
    x = dpp_add<0x111>(x);  // row_shr:1
    x = dpp_add<0x112>(x);  // row_shr:2
    x = dpp_add<0x114>(x);  // row_shr:4
    x = dpp_add<0x118>(x);  // row_shr:8
    x = dpp_add<0x142>(x);  // row_bcast:15
    x = dpp_add<0x143>(x);  // row_bcast:31
    return x;
}

__device__ __forceinline__ float readlane_f(float x, int l) {
    return __int_as_float(__builtin_amdgcn_readlane(__float_as_int(x), l));
}

__global__ __launch_bounds__(256) void sgd_filter_kernel(const float* __restrict__ tgt,
                                                         float* __restrict__ out) {
    const int tid  = threadIdx.x;      // 0..255
    const int lane = tid & 63;
    const int wv   = tid >> 6;         // wave 0..3

    // two frequencies per lane: f0 = tid, f1 = tid + 256
    const float wA = (float)(3.14159265358979323846 * (double)tid / 511.0);
    const float wB = (float)(3.14159265358979323846 * (double)(tid + 256) / 511.0);
    float s1a, c1a, s1b, c1b;
    sincosf(wA, &s1a, &c1a);
    sincosf(wB, &s1b, &c1b);
    const float c2a = c1a * c1a - s1a * s1a, s2a = 2.0f * c1a * s1a;
    const float c2b = c1b * c1b - s1b * s1b, s2b = 2.0f * c1b * s1b;
    const float tka = tgt[tid] * INVK_;        // tg / K
    const float tkb = tgt[tid + 256] * INVK_;

    // lane-replicated parameters
    float q0  = 1.0f;
    float qpr = 1.0f, qpi = 1.0f;
    float qzr = 1.0f, qzi = 1.0f;

    __shared__ float part[2][32];      // [pp][wv*8 + l], l = 0..4

    const int widx = wv << 3;                               // write base
    const int ridx = (((lane & 3) << 3) | (lane >> 2)) & 31; // read idx (valid lanes 0..19)

#define PERFREQ(C1, S1, C2, S2, TGK)                                  \
        {                                                             \
            float Br = b0 + b1 * C1 + b2 * C2;                        \
            float Bi = -(b1 * S1 + b2 * S2);                          \
            float Ar = 1.0f + a1 * C1 + a2 * C2;                      \
            float Ai = -(a1 * S1 + a2 * S2);                          \
            float nb = Br * Br + Bi * Bi;                             \
            float na = Ar * Ar + Ai * Ai;                             \
            float rnb = rcp_(nb);                                     \
            float rna = rcp_(na);                                     \
            float r  = nb * rna;                                      \
            float r2 = r * r;                                         \
            float r4 = r2 * r2;                                       \
            float m  = r4 * r4;                                       \
            float mp = m + EPSF;                                      \
            float cF = LRKC_ * (log2_(mp) - TGK) * (m * rcp_(mp));    \
            float cb = cF * rnb;                                      \
            float ca = cF * rna;                                      \
            float cbBr = cb * Br, cbBi = cb * Bi;                     \
            float caAr = ca * Ar, caAi = ca * Ai;                     \
            gb0 += cbBr;                                              \
            gb1 += cbBr * C1 - cbBi * S1;                             \
            gb2 += cbBr * C2 - cbBi * S2;                             \
            ga1 -= caAr * C1 - caAi * S1;                             \
            ga2 -= caAr * C2 - caAi * S2;                             \
        }

#define STEP(PP)                                                      \
    {                                                                 \
        float g   = q0 + 1.0f;                                        \
        float pu  = sqrt_(qpr * qpr + qpi * qpi);                     \
        float ipu = rcp_(pu);                                         \
        float tp  = tanh_pos(pu);                                     \
        float psc = tp * ipu;                                         \
        float prs = qpr * psc, pis = qpi * psc;                       \
        float zu  = sqrt_(qzr * qzr + qzi * qzi);                     \
        float izu = rcp_(zu);                                         \
        float tz  = tanh_pos(zu);                                     \
        float zsc = tz * izu;                                         \
        float zrs = qzr * zsc, zis = qzi * zsc;                       \
        float b0 = g;                                                 \
        float b1 = -2.0f * g * zrs;                                   \
        float zq = tz * tz;                                           \
        float b2 = g * zq;                                            \
        float a1 = -2.0f * prs;                                       \
        float a2 = tp * tp;                                           \
        float gb0 = 0.0f, gb1 = 0.0f, gb2 = 0.0f, ga1 = 0.0f, ga2 = 0.0f; \
        PERFREQ(c1a, s1a, c2a, s2a, tka)                              \
        PERFREQ(c1b, s1b, c2b, s2b, tkb)                              \
        float t0 = wave_sum_at63(gb0);                                \
        float t1 = wave_sum_at63(gb1);                                \
        float t2 = wave_sum_at63(gb2);                                \
        float t3 = wave_sum_at63(gb2 = ga1);                          \
        float t4 = wave_sum_at63(ga2);                                \
        if (lane == 63) {                                             \
            float* pb = &part[PP][widx];                              \
            pb[0] = t0; pb[1] = t1; pb[2] = t2; pb[3] = t3; pb[4] = t4; \
        }                                                             \
        __syncthreads();                                              \
        float y = part[PP][ridx];                                     \
        y = dpp_add<0x111>(y);                                        \
        y = dpp_add<0x112>(y);                                        \
        float S0 = readlane_f(y, 3);                                  \
        float S1 = readlane_f(y, 7);                                  \
        float S2 = readlane_f(y, 11);                                 \
        float S3 = readlane_f(y, 15);                                 \
        float S4 = readlane_f(y, 19);                                 \
        float dg  = S0 - 2.0f * zrs * S1 + zq * S2;                   \
        float dzr = 2.0f * g * (zrs * S2 - S1);                       \
        float dzi = 2.0f * g * zis * S2;                              \
        float dpr = 2.0f * (prs * S4 - S3);                           \
        float dpi = 2.0f * pis * S4;                                  \
        float zds  = ((1.0f - zq) - tz * izu) * izu;                  \
        float zdot = qzr * dzr + qzi * dzi;                           \
        float zcom = zds * izu * zdot;                                \
        float gzr  = zsc * dzr + qzr * zcom;                          \
        float gzi  = zsc * dzi + qzi * zcom;                          \
        float pds  = ((1.0f - a2) - tp * ipu) * ipu;                  \
        float pdot = qpr * dpr + qpi * dpi;                           \
        float pcom = pds * ipu * pdot;                                \
        float gpr  = psc * dpr + qpr * pcom;                          \
        float gpi  = psc * dpi + qpi * pcom;                          \
        q0  -= dg;                                                    \
        qpr -= gpr;  qpi -= gpi;                                      \
        qzr -= gzr;  qzi -= gzi;                                      \
    }

    // 999 iterations = 499 x (STEP(0); STEP(1)) + STEP(0)
    for (int it = 0; it < 499; ++it) {
        STEP(0)
        STEP(1)
    }
    STEP(0)

#undef STEP
#undef PERFREQ

    // ---- final pz_to_sos, 16 identical sections ----
    {
        float g   = q0 + 1.0f;
        float pu  = sqrt_(qpr * qpr + qpi * qpi);
        float psc = tanh_pos(pu) * rcp_(pu);
        float prs = qpr * psc, pis = qpi * psc;
        float zu  = sqrt_(qzr * qzr + qzi * qzi);
        float zsc = tanh_pos(zu) * rcp_(zu);
        float zrs = qzr * zsc, zis = qzi * zsc;
        float b0 = g;
        float b1 = -2.0f * g * zrs;
        float b2 = g * (zrs * zrs + zis * zis);
        float a1 = -2.0f * prs;
        float a2 = prs * prs + pis * pis;
        if (tid < 96) {
            int c = tid % 6;
            float v = (c == 0) ? b0 : (c == 1) ? b1 : (c == 2) ? b2
                    : (c == 3) ? 1.0f : (c == 4) ? a1 : a2;
            out[tid] = v;
        }
    }
}

extern "C" void kernel_launch(void* const* d_in, const int* in_sizes, int n_in,
                              void* d_out, int out_size, void* d_ws, size_t ws_size,
                              hipStream_t stream) {
    (void)in_sizes; (void)n_in; (void)d_ws; (void)ws_size; (void)out_size;
    const float* tgt = (const float*)d_in[0];
    float* out = (float*)d_out;
    hipLaunchKernelGGL(sgd_filter_kernel, dim3(1), dim3(256), 0, stream, tgt, out);
}